// Round 1
// baseline (675.832 us; speedup 1.0000x reference)
//
#include <hip/hip_runtime.h>
#include <math.h>

#define BB 2
#define CIN 256
#define DDEP 32
#define HWXY 1024
#define SS 32768
#define NHEADS 8

// ---------------------------------------------------------------------------
// K1: conv1x1, transposed output: out_t[b, s, o] = sum_c w[o,c]*x[b,c,s] + bias[o]
// 128x128 tile, K-step 32, 256 threads, 8x8 acc per thread.
// ---------------------------------------------------------------------------
template<int O, int OT>
__global__ __launch_bounds__(256)
void conv1x1_t_kernel(const float* __restrict__ x,
                      const float* __restrict__ w,
                      const float* __restrict__ bias,
                      float* __restrict__ out_t)
{
    __shared__ float xs[32][128];      // [kc][s]
    __shared__ float ws[32][132];      // [kc][o] padded
    const int b = blockIdx.y;
    const int s_tile = blockIdx.x / OT;
    const int o_tile = blockIdx.x % OT;
    const int s0 = s_tile * 128, o0 = o_tile * 128;
    const int t = threadIdx.x;
    const int ti = t & 15, tj = t >> 4;

    float acc[8][8];
#pragma unroll
    for (int i = 0; i < 8; i++)
#pragma unroll
        for (int j = 0; j < 8; j++) acc[i][j] = 0.f;

    const float* xb = x + (size_t)b * CIN * SS;
    for (int c0 = 0; c0 < CIN; c0 += 32) {
#pragma unroll
        for (int l = 0; l < 4; l++) {
            int idx = t + l * 256;
            int row = idx >> 5, col4 = idx & 31;
            float4 v = *(const float4*)(xb + (size_t)(c0 + row) * SS + s0 + col4 * 4);
            *(float4*)(&xs[row][col4 * 4]) = v;
        }
#pragma unroll
        for (int l = 0; l < 4; l++) {
            int idx = t + l * 256;
            int o = idx >> 3, c4 = idx & 7;
            float4 v = *(const float4*)(w + (size_t)(o0 + o) * CIN + c0 + c4 * 4);
            ws[c4 * 4 + 0][o] = v.x;
            ws[c4 * 4 + 1][o] = v.y;
            ws[c4 * 4 + 2][o] = v.z;
            ws[c4 * 4 + 3][o] = v.w;
        }
        __syncthreads();
#pragma unroll
        for (int kc = 0; kc < 32; kc++) {
            float a[8], bv[8];
            *(float4*)&a[0] = *(const float4*)&xs[kc][ti * 8];
            *(float4*)&a[4] = *(const float4*)&xs[kc][ti * 8 + 4];
            *(float4*)&bv[0] = *(const float4*)&ws[kc][tj * 8];
            *(float4*)&bv[4] = *(const float4*)&ws[kc][tj * 8 + 4];
#pragma unroll
            for (int i = 0; i < 8; i++)
#pragma unroll
                for (int j = 0; j < 8; j++)
                    acc[i][j] = fmaf(a[i], bv[j], acc[i][j]);
        }
        __syncthreads();
    }
    float bv[8];
    *(float4*)&bv[0] = *(const float4*)(bias + o0 + tj * 8);
    *(float4*)&bv[4] = *(const float4*)(bias + o0 + tj * 8 + 4);
    float* ob = out_t + ((size_t)b * SS + s0) * O + o0;
#pragma unroll
    for (int i = 0; i < 8; i++) {
        float v0[4], v1[4];
#pragma unroll
        for (int j = 0; j < 4; j++) v0[j] = acc[i][j] + bv[j];
#pragma unroll
        for (int j = 0; j < 4; j++) v1[j] = acc[i][4 + j] + bv[4 + j];
        *(float4*)(ob + (size_t)(ti * 8 + i) * O + tj * 8) = *(float4*)v0;
        *(float4*)(ob + (size_t)(ti * 8 + i) * O + tj * 8 + 4) = *(float4*)v1;
    }
}

// ---------------------------------------------------------------------------
// K2: attention logits.  L[b,nh,i,j] += sum_{hw in chunk, kd} q_t[b,i,hw,nh*64+kd]
//                                        * kv_t[b,j,hw,kd]
// grid: (hw_chunk=32, nh=8, b=2). 256 threads -> 2x2 acc each (32x32 tile).
// ---------------------------------------------------------------------------
__global__ __launch_bounds__(256)
void attn_logits_kernel(const float* __restrict__ q_t,
                        const float* __restrict__ kv_t,
                        float* __restrict__ Lbuf)
{
    __shared__ float qs[32][68];
    __shared__ float ks[32][68];
    const int hw0 = blockIdx.x * 32;
    const int nh = blockIdx.y;
    const int b = blockIdx.z;
    const int t = threadIdx.x;
    const int ti = t & 15, tj = t >> 4;
    float a00 = 0.f, a01 = 0.f, a10 = 0.f, a11 = 0.f;
    for (int hh = 0; hh < 32; hh++) {
        const int hw = hw0 + hh;
#pragma unroll
        for (int l = 0; l < 2; l++) {
            int idx = t + l * 256;
            int i = idx >> 4, kd4 = idx & 15;
            float4 v = *(const float4*)(q_t + ((size_t)((b * 32 + i) * 1024 + hw)) * 512 + nh * 64 + kd4 * 4);
            *(float4*)(&qs[i][kd4 * 4]) = v;
        }
#pragma unroll
        for (int l = 0; l < 2; l++) {
            int idx = t + l * 256;
            int j = idx >> 4, kd4 = idx & 15;
            float4 v = *(const float4*)(kv_t + ((size_t)((b * 32 + j) * 1024 + hw)) * 128 + kd4 * 4);
            *(float4*)(&ks[j][kd4 * 4]) = v;
        }
        __syncthreads();
#pragma unroll
        for (int kd4 = 0; kd4 < 16; kd4++) {
            float4 x0 = *(const float4*)(&qs[ti][kd4 * 4]);
            float4 x1 = *(const float4*)(&qs[ti + 16][kd4 * 4]);
            float4 y0 = *(const float4*)(&ks[tj][kd4 * 4]);
            float4 y1 = *(const float4*)(&ks[tj + 16][kd4 * 4]);
            a00 = fmaf(x0.x, y0.x, a00); a00 = fmaf(x0.y, y0.y, a00);
            a00 = fmaf(x0.z, y0.z, a00); a00 = fmaf(x0.w, y0.w, a00);
            a01 = fmaf(x0.x, y1.x, a01); a01 = fmaf(x0.y, y1.y, a01);
            a01 = fmaf(x0.z, y1.z, a01); a01 = fmaf(x0.w, y1.w, a01);
            a10 = fmaf(x1.x, y0.x, a10); a10 = fmaf(x1.y, y0.y, a10);
            a10 = fmaf(x1.z, y0.z, a10); a10 = fmaf(x1.w, y0.w, a10);
            a11 = fmaf(x1.x, y1.x, a11); a11 = fmaf(x1.y, y1.y, a11);
            a11 = fmaf(x1.z, y1.z, a11); a11 = fmaf(x1.w, y1.w, a11);
        }
        __syncthreads();
    }
    float* Lb = Lbuf + (size_t)(b * 8 + nh) * 1024;
    atomicAdd(&Lb[ti * 32 + tj], a00);
    atomicAdd(&Lb[ti * 32 + tj + 16], a01);
    atomicAdd(&Lb[(ti + 16) * 32 + tj], a10);
    atomicAdd(&Lb[(ti + 16) * 32 + tj + 16], a11);
}

// ---------------------------------------------------------------------------
// K3: softmax over j (32) for each of 512 rows, with scale = VD^-0.5 = 0.125
// ---------------------------------------------------------------------------
__global__ __launch_bounds__(256)
void softmax_kernel(float* __restrict__ Lbuf)
{
    int r = blockIdx.x * 256 + threadIdx.x;
    if (r >= 512) return;
    float* row = Lbuf + (size_t)r * 32;
    float p[32];
#pragma unroll
    for (int j = 0; j < 32; j++) p[j] = row[j];
    float m = p[0];
#pragma unroll
    for (int j = 1; j < 32; j++) m = fmaxf(m, p[j]);
    float s = 0.f;
#pragma unroll
    for (int j = 0; j < 32; j++) { p[j] = expf((p[j] - m) * 0.125f); s += p[j]; }
    float inv = 1.f / s;
#pragma unroll
    for (int j = 0; j < 32; j++) row[j] = p[j] * inv;
}

// ---------------------------------------------------------------------------
// K4: o_r[b, s'=(d,h,w), c'] = sum_j attn[b, h>>2, d, j]
//                              * kv_t[b, j, (h&3)*256 + w*8 + (c'>>6), 64+(c'&63)]
// grid: (w=32, hl=4, b=2). v fragment held in 128 VGPRs; attn staged in LDS.
// Output layout o_rt[b][s'][c'] (c' contiguous) for the proj GEMM.
// ---------------------------------------------------------------------------
__global__ __launch_bounds__(256)
void attn_v_kernel(const float* __restrict__ kv_t,
                   const float* __restrict__ attn,
                   float* __restrict__ o_rt)
{
    __shared__ float as[8 * 32 * 32];   // [nh][d][j] = 32 KB
    const int wq = blockIdx.x, hl = blockIdx.y, b = blockIdx.z;
    const int t = threadIdx.x;
    {
        const float* src = attn + (size_t)b * 8192;
#pragma unroll
        for (int l = 0; l < 8; l++) {
            int idx = (t + l * 256) * 4;
            *(float4*)(&as[idx]) = *(const float4*)(src + idx);
        }
    }
    __syncthreads();
    const int q4 = t & 127;             // c' quad: c' = q4*4
    const int half = t >> 7;            // rows 0..127 / 128..255
    const int tt = q4 >> 4;             // c'>>6
    const int vd = (q4 * 4) & 63;       // c'&63 base
    const int hw = hl * 256 + wq * 8 + tt;
    float4 vreg[32];
#pragma unroll
    for (int j = 0; j < 32; j++)
        vreg[j] = *(const float4*)(kv_t + ((size_t)((b * 32 + j) * 1024 + hw)) * 128 + 64 + vd);
    float* outb = o_rt + (size_t)b * SS * 512;
#pragma unroll 2
    for (int r = 0; r < 128; r++) {
        int row = half * 128 + r;       // row = nh*32 + d
        int hh = row >> 5, d = row & 31;
        const float* arow = &as[row * 32];
        float ax = 0.f, ay = 0.f, az = 0.f, aw = 0.f;
#pragma unroll
        for (int j4 = 0; j4 < 8; j4++) {
            float4 a4 = *(const float4*)(&arow[j4 * 4]);
            float4 v0 = vreg[j4 * 4 + 0];
            float4 v1 = vreg[j4 * 4 + 1];
            float4 v2 = vreg[j4 * 4 + 2];
            float4 v3 = vreg[j4 * 4 + 3];
            ax = fmaf(a4.x, v0.x, ax); ay = fmaf(a4.x, v0.y, ay);
            az = fmaf(a4.x, v0.z, az); aw = fmaf(a4.x, v0.w, aw);
            ax = fmaf(a4.y, v1.x, ax); ay = fmaf(a4.y, v1.y, ay);
            az = fmaf(a4.y, v1.z, az); aw = fmaf(a4.y, v1.w, aw);
            ax = fmaf(a4.z, v2.x, ax); ay = fmaf(a4.z, v2.y, ay);
            az = fmaf(a4.z, v2.z, az); aw = fmaf(a4.z, v2.w, aw);
            ax = fmaf(a4.w, v3.x, ax); ay = fmaf(a4.w, v3.y, ay);
            az = fmaf(a4.w, v3.z, az); aw = fmaf(a4.w, v3.w, aw);
        }
        int hp = hh * 4 + hl;
        size_t sp = (size_t)d * 1024 + hp * 32 + wq;
        float4 o4 = make_float4(ax, ay, az, aw);
        *(float4*)(outb + sp * 512 + q4 * 4) = o4;
    }
}

// ---------------------------------------------------------------------------
// K5: proj GEMM + bias + layer_scale.
// out[b, co, s'] = (sum_c' proj_w[co,c'] * o_rt[b,s',c'] + proj_b[co]) * ls[co]
// 128x128 tile, K=512 in steps of 32.
// ---------------------------------------------------------------------------
__global__ __launch_bounds__(256)
void proj_kernel(const float* __restrict__ o_rt,
                 const float* __restrict__ w,
                 const float* __restrict__ bias,
                 const float* __restrict__ ls,
                 float* __restrict__ out)
{
    __shared__ float xs[32][132];   // [kc][n] transposed
    __shared__ float ws[32][132];   // [kc][o]
    const int b = blockIdx.y;
    const int o_tile = blockIdx.x & 1;
    const int n_tile = blockIdx.x >> 1;
    const int n0 = n_tile * 128, o0 = o_tile * 128;
    const int t = threadIdx.x;
    const int ti = t & 15, tj = t >> 4;
    float acc[8][8];
#pragma unroll
    for (int i = 0; i < 8; i++)
#pragma unroll
        for (int j = 0; j < 8; j++) acc[i][j] = 0.f;

    const float* xb = o_rt + (size_t)b * SS * 512;
    for (int c0 = 0; c0 < 512; c0 += 32) {
#pragma unroll
        for (int l = 0; l < 4; l++) {
            int idx = t + l * 256;
            int n = idx >> 3, c4 = idx & 7;
            float4 v = *(const float4*)(xb + (size_t)(n0 + n) * 512 + c0 + c4 * 4);
            xs[c4 * 4 + 0][n] = v.x;
            xs[c4 * 4 + 1][n] = v.y;
            xs[c4 * 4 + 2][n] = v.z;
            xs[c4 * 4 + 3][n] = v.w;
        }
#pragma unroll
        for (int l = 0; l < 4; l++) {
            int idx = t + l * 256;
            int o = idx >> 3, c4 = idx & 7;
            float4 v = *(const float4*)(w + (size_t)(o0 + o) * 512 + c0 + c4 * 4);
            ws[c4 * 4 + 0][o] = v.x;
            ws[c4 * 4 + 1][o] = v.y;
            ws[c4 * 4 + 2][o] = v.z;
            ws[c4 * 4 + 3][o] = v.w;
        }
        __syncthreads();
#pragma unroll
        for (int kc = 0; kc < 32; kc++) {
            float a[8], bv[8];
            *(float4*)&a[0] = *(const float4*)&xs[kc][ti * 8];
            *(float4*)&a[4] = *(const float4*)&xs[kc][ti * 8 + 4];
            *(float4*)&bv[0] = *(const float4*)&ws[kc][tj * 8];
            *(float4*)&bv[4] = *(const float4*)&ws[kc][tj * 8 + 4];
#pragma unroll
            for (int i = 0; i < 8; i++)
#pragma unroll
                for (int j = 0; j < 8; j++)
                    acc[i][j] = fmaf(a[i], bv[j], acc[i][j]);
        }
        __syncthreads();
    }
    float bv[8], lv[8];
#pragma unroll
    for (int j = 0; j < 8; j++) {
        bv[j] = bias[o0 + tj * 8 + j];
        lv[j] = ls[o0 + tj * 8 + j];
    }
    float* ob = out + ((size_t)b * 256 + o0) * SS + n0;
#pragma unroll
    for (int j = 0; j < 8; j++) {
        float v0[4], v1[4];
#pragma unroll
        for (int i = 0; i < 4; i++) v0[i] = (acc[i][j] + bv[j]) * lv[j];
#pragma unroll
        for (int i = 0; i < 4; i++) v1[i] = (acc[4 + i][j] + bv[j]) * lv[j];
        *(float4*)(ob + (size_t)(tj * 8 + j) * SS + ti * 8) = *(float4*)v0;
        *(float4*)(ob + (size_t)(tj * 8 + j) * SS + ti * 8 + 4) = *(float4*)v1;
    }
}

extern "C" void kernel_launch(void* const* d_in, const int* in_sizes, int n_in,
                              void* d_out, int out_size, void* d_ws, size_t ws_size,
                              hipStream_t stream)
{
    const float* x      = (const float*)d_in[0];
    const float* q_w    = (const float*)d_in[1];
    const float* q_b    = (const float*)d_in[2];
    const float* kv_w   = (const float*)d_in[3];
    const float* kv_b   = (const float*)d_in[4];
    const float* proj_w = (const float*)d_in[5];
    const float* proj_b = (const float*)d_in[6];
    const float* ls     = (const float*)d_in[7];
    float* out = (float*)d_out;

    char* ws = (char*)d_ws;
    float* kv_t = (float*)ws;                               // 2*32768*128*4 = 33,554,432 B
    float* Lbuf = (float*)(ws + 33554432);                  // 2*8*32*32*4  =    262,144 B
    float* q_t  = (float*)(ws + 33554432 + 262144);         // 2*32768*512*4 = 134,217,728 B
    float* o_rt = q_t;  // q_t dead after attn_logits; reuse region for o_rt

    hipMemsetAsync(Lbuf, 0, (size_t)BB * 8 * 32 * 32 * sizeof(float), stream);

    // q conv: O=512, 4 o-tiles
    conv1x1_t_kernel<512, 4><<<dim3(1024, 2), 256, 0, stream>>>(x, q_w, q_b, q_t);
    // kv conv: O=128, 1 o-tile
    conv1x1_t_kernel<128, 1><<<dim3(256, 2), 256, 0, stream>>>(x, kv_w, kv_b, kv_t);
    // attention logits (atomic partial sums over hw chunks)
    attn_logits_kernel<<<dim3(32, 8, 2), 256, 0, stream>>>(q_t, kv_t, Lbuf);
    // softmax
    softmax_kernel<<<dim3(2), 256, 0, stream>>>(Lbuf);
    // attn @ v with torch-exact reorder, into o_rt[b][s'][c']
    attn_v_kernel<<<dim3(32, 4, 2), 256, 0, stream>>>(kv_t, Lbuf, o_rt);
    // proj + bias + layer_scale
    proj_kernel<<<dim3(512, 2), 256, 0, stream>>>(o_rt, proj_w, proj_b, ls, out);
}

// Round 2
// 284.172 us; speedup vs baseline: 2.3783x; 2.3783x over previous
//
#include <hip/hip_runtime.h>
#include <math.h>

#define SS 32768

typedef _Float16 half4v __attribute__((ext_vector_type(4)));
typedef _Float16 half8v __attribute__((ext_vector_type(8)));
typedef float float4v __attribute__((ext_vector_type(4)));

__device__ __forceinline__ void gload16(const void* g, void* l) {
    __builtin_amdgcn_global_load_lds(
        (const __attribute__((address_space(1))) unsigned int*)g,
        (__attribute__((address_space(3))) unsigned int*)l, 16, 0, 0);
}

// ---------------------------------------------------------------------------
// K0a: x[b][c][s] fp32 -> x_t[b][s][c] fp16 (LDS tile transpose)
// ---------------------------------------------------------------------------
__global__ __launch_bounds__(256)
void cvt_x_kernel(const float* __restrict__ x, _Float16* __restrict__ x_t)
{
    __shared__ float ls[64][65];
    const int b = blockIdx.z, c0 = blockIdx.y * 64, s0 = blockIdx.x * 64;
    const int t = threadIdx.x;
    const int tr = t >> 4, tc = t & 15;
#pragma unroll
    for (int p = 0; p < 4; p++) {
        int c_l = p * 16 + tr;
        float4v v = *(const float4v*)(x + (size_t)(b * 256 + c0 + c_l) * SS + s0 + tc * 4);
        ls[c_l][tc * 4 + 0] = v.x;
        ls[c_l][tc * 4 + 1] = v.y;
        ls[c_l][tc * 4 + 2] = v.z;
        ls[c_l][tc * 4 + 3] = v.w;
    }
    __syncthreads();
#pragma unroll
    for (int p = 0; p < 4; p++) {
        int s_l = p * 16 + tr;
        half4v h;
        h.x = (_Float16)ls[tc * 4 + 0][s_l];
        h.y = (_Float16)ls[tc * 4 + 1][s_l];
        h.z = (_Float16)ls[tc * 4 + 2][s_l];
        h.w = (_Float16)ls[tc * 4 + 3][s_l];
        *(half4v*)(x_t + ((size_t)b * SS + s0 + s_l) * 256 + c0 + tc * 4) = h;
    }
}

// ---------------------------------------------------------------------------
// K0b: fp32 -> fp16 cast (weights). n is a multiple of 1024; grid = n/1024.
// ---------------------------------------------------------------------------
__global__ __launch_bounds__(256)
void cvt_w_kernel(const float* __restrict__ src, _Float16* __restrict__ dst)
{
    int i = (blockIdx.x * 256 + threadIdx.x) * 4;
    float4v v = *(const float4v*)(src + i);
    half4v h;
    h.x = (_Float16)v.x; h.y = (_Float16)v.y; h.z = (_Float16)v.z; h.w = (_Float16)v.w;
    *(half4v*)(dst + i) = h;
}

// ---------------------------------------------------------------------------
// K1: fused q+kv conv via MFMA. out_t[b,s,o] = sum_c W[o,c]*x_t[b,s,c] + bias
// block tile 128(o) x 128(s), K=256 in steps of 32. o_tile 0-3 -> q, 4 -> kv.
// Staging via global_load_lds width-16 (wave-uniform LDS base + lane*16).
// ---------------------------------------------------------------------------
__global__ __launch_bounds__(256)
void conv_mfma_kernel(const _Float16* __restrict__ x_t,
                      const _Float16* __restrict__ wq,
                      const _Float16* __restrict__ wkv,
                      const float* __restrict__ q_b,
                      const float* __restrict__ kv_b,
                      _Float16* __restrict__ q_t,
                      _Float16* __restrict__ kv_t)
{
    __shared__ _Float16 Ws[128 * 32];
    __shared__ _Float16 Xs[128 * 32];
    const int b = blockIdx.y;
    const int s_tile = blockIdx.x / 5;
    const int o_tile = blockIdx.x % 5;
    const int s0 = s_tile * 128;
    const bool is_q = (o_tile < 4);
    const _Float16* W = is_q ? wq : wkv;
    const float* bias = is_q ? q_b : kv_b;
    const int od0 = is_q ? o_tile * 128 : 0;
    const int ODST = is_q ? 512 : 128;
    _Float16* dst = is_q ? q_t : kv_t;

    const int t = threadIdx.x;
    const int w = t >> 6, l = t & 63;
    const int om = (w & 1) * 64, sn = (w >> 1) * 64;

    float4v acc[4][4];
#pragma unroll
    for (int i = 0; i < 4; i++)
#pragma unroll
        for (int j = 0; j < 4; j++) acc[i][j] = (float4v){0.f, 0.f, 0.f, 0.f};

    const _Float16* wg0 = W + (size_t)(od0 + 32 * w + (l >> 2)) * 256 + (l & 3) * 8;
    const _Float16* xg0 = x_t + ((size_t)b * SS + s0 + 32 * w + (l >> 2)) * 256 + (l & 3) * 8;
    _Float16* wl = &Ws[(32 * w) * 32];
    _Float16* xl = &Xs[(32 * w) * 32];

    for (int c0 = 0; c0 < 256; c0 += 32) {
        gload16(wg0 + c0, wl);
        gload16(wg0 + 16 * 256 + c0, wl + 16 * 32);
        gload16(xg0 + c0, xl);
        gload16(xg0 + 16 * 256 + c0, xl + 16 * 32);
        __syncthreads();
        half8v a[4], bb[4];
#pragma unroll
        for (int i = 0; i < 4; i++)
            a[i] = *(const half8v*)&Ws[(om + i * 16 + (l & 15)) * 32 + (l >> 4) * 8];
#pragma unroll
        for (int j = 0; j < 4; j++)
            bb[j] = *(const half8v*)&Xs[(sn + j * 16 + (l & 15)) * 32 + (l >> 4) * 8];
#pragma unroll
        for (int i = 0; i < 4; i++)
#pragma unroll
            for (int j = 0; j < 4; j++)
                acc[i][j] = __builtin_amdgcn_mfma_f32_16x16x32_f16(a[i], bb[j], acc[i][j], 0, 0, 0);
        __syncthreads();
    }
    // epilogue: D col = lane&15 (s), row = (lane>>4)*4 + reg (o)
    const int qd = l >> 4, m = l & 15;
#pragma unroll
    for (int i = 0; i < 4; i++) {
        float bv[4];
#pragma unroll
        for (int r = 0; r < 4; r++) bv[r] = bias[od0 + om + i * 16 + qd * 4 + r];
#pragma unroll
        for (int j = 0; j < 4; j++) {
            half4v h;
            h.x = (_Float16)(acc[i][j].x + bv[0]);
            h.y = (_Float16)(acc[i][j].y + bv[1]);
            h.z = (_Float16)(acc[i][j].z + bv[2]);
            h.w = (_Float16)(acc[i][j].w + bv[3]);
            size_t s = (size_t)b * SS + s0 + sn + j * 16 + m;
            *(half4v*)(dst + s * ODST + od0 + om + i * 16 + qd * 4) = h;
        }
    }
}

// ---------------------------------------------------------------------------
// K2: attention logits via MFMA. L[b,nh,i,j] = sum_{hw,kd} q[i,hw,kd]*k[j,hw,kd]
// grid (hwc=32, nh=8, b=2); each block does 32 hw x 64 kd of K; atomicAdd.
// Wave w computes frag quadrant (mi=(w&1)*16, nj=(w>>1)*16).
// ---------------------------------------------------------------------------
__global__ __launch_bounds__(256)
void logits_mfma_kernel(const _Float16* __restrict__ q_t,
                        const _Float16* __restrict__ kv_t,
                        float* __restrict__ Lbuf)
{
    __shared__ _Float16 Qs[32 * 64];
    __shared__ _Float16 Ks[32 * 64];
    const int hwc = blockIdx.x, nh = blockIdx.y, b = blockIdx.z;
    const int t = threadIdx.x, w = t >> 6, l = t & 63;
    const int mi = (w & 1) * 16, nj = (w >> 1) * 16;

    // staging roles: wave0: Q rows 0-15, wave1: Q rows 16-31, wave2: K 0-15, wave3: K 16-31
    const int rhalf = w & 1;
    const bool isK = (w >> 1) != 0;
    const int rrow = rhalf * 16 + (l >> 3);   // first call rows; second call +8
    const int ch = l & 7;
    _Float16* lbase = (isK ? Ks : Qs) + (rhalf * 16) * 64;

    float4v acc = (float4v){0.f, 0.f, 0.f, 0.f};

    for (int hh = 0; hh < 32; hh++) {
        const int hw = hwc * 32 + hh;
        if (!isK) {
            const _Float16* g = q_t + ((size_t)b * SS + (size_t)rrow * 1024 + hw) * 512 + nh * 64 + ch * 8;
            gload16(g, lbase);
            gload16(g + (size_t)8 * 1024 * 512, lbase + 8 * 64);
        } else {
            const _Float16* g = kv_t + ((size_t)b * SS + (size_t)rrow * 1024 + hw) * 128 + ch * 8;
            gload16(g, lbase);
            gload16(g + (size_t)8 * 1024 * 128, lbase + 8 * 64);
        }
        __syncthreads();
#pragma unroll
        for (int ks = 0; ks < 2; ks++) {
            half8v a = *(const half8v*)&Qs[(mi + (l & 15)) * 64 + ks * 32 + (l >> 4) * 8];
            half8v bb = *(const half8v*)&Ks[(nj + (l & 15)) * 64 + ks * 32 + (l >> 4) * 8];
            acc = __builtin_amdgcn_mfma_f32_16x16x32_f16(a, bb, acc, 0, 0, 0);
        }
        __syncthreads();
    }
    float* Lb = Lbuf + (size_t)(b * 8 + nh) * 1024;
    const int row = mi + (l >> 4) * 4, col = nj + (l & 15);
#pragma unroll
    for (int rr = 0; rr < 4; rr++)
        atomicAdd(&Lb[(row + rr) * 32 + col], acc[rr]);
}

// ---------------------------------------------------------------------------
// K3: softmax over j (32) for each of 512 rows, scale = VD^-0.5 = 0.125
// ---------------------------------------------------------------------------
__global__ __launch_bounds__(256)
void softmax_kernel(float* __restrict__ Lbuf)
{
    int r = blockIdx.x * 256 + threadIdx.x;
    if (r >= 512) return;
    float* row = Lbuf + (size_t)r * 32;
    float p[32];
#pragma unroll
    for (int j = 0; j < 32; j++) p[j] = row[j];
    float m = p[0];
#pragma unroll
    for (int j = 1; j < 32; j++) m = fmaxf(m, p[j]);
    float s = 0.f;
#pragma unroll
    for (int j = 0; j < 32; j++) { p[j] = expf((p[j] - m) * 0.125f); s += p[j]; }
    float inv = 1.f / s;
#pragma unroll
    for (int j = 0; j < 32; j++) row[j] = p[j] * inv;
}

// ---------------------------------------------------------------------------
// K4: o_t[b, s'=(d,h,w), c'] = sum_j attn[b, h>>2, d, j]
//        * kv_t[b, j, (h&3)*256 + w*8 + (c'>>6), 64+(c'&63)]   (fp16 in/out)
// ---------------------------------------------------------------------------
__global__ __launch_bounds__(256)
void attn_v_kernel(const _Float16* __restrict__ kv_t,
                   const float* __restrict__ attn,
                   _Float16* __restrict__ o_t)
{
    __shared__ float as_[8 * 32 * 32];
    const int wq = blockIdx.x, hl = blockIdx.y, b = blockIdx.z;
    const int t = threadIdx.x;
    {
        const float* src = attn + (size_t)b * 8192;
#pragma unroll
        for (int ll = 0; ll < 8; ll++) {
            int idx = (t + ll * 256) * 4;
            *(float4v*)(&as_[idx]) = *(const float4v*)(src + idx);
        }
    }
    __syncthreads();
    const int q4 = t & 127;
    const int half = t >> 7;
    const int tt = q4 >> 4;
    const int vd = (q4 * 4) & 63;
    const int hw = hl * 256 + wq * 8 + tt;
    float4v vreg[32];
#pragma unroll
    for (int j = 0; j < 32; j++) {
        half4v hv = *(const half4v*)(kv_t + ((size_t)((b * 32 + j) * 1024 + hw)) * 128 + 64 + vd);
        vreg[j] = (float4v){(float)hv.x, (float)hv.y, (float)hv.z, (float)hv.w};
    }
    _Float16* outb = o_t + (size_t)b * SS * 512;
#pragma unroll 2
    for (int rr = 0; rr < 128; rr++) {
        int row = half * 128 + rr;
        int hh = row >> 5, d = row & 31;
        const float* arow = &as_[row * 32];
        float ax = 0.f, ay = 0.f, az = 0.f, aw = 0.f;
#pragma unroll
        for (int j4 = 0; j4 < 8; j4++) {
            float4v a4 = *(const float4v*)(&arow[j4 * 4]);
            float4v v0 = vreg[j4 * 4 + 0];
            float4v v1 = vreg[j4 * 4 + 1];
            float4v v2 = vreg[j4 * 4 + 2];
            float4v v3 = vreg[j4 * 4 + 3];
            ax = fmaf(a4.x, v0.x, ax); ay = fmaf(a4.x, v0.y, ay);
            az = fmaf(a4.x, v0.z, az); aw = fmaf(a4.x, v0.w, aw);
            ax = fmaf(a4.y, v1.x, ax); ay = fmaf(a4.y, v1.y, ay);
            az = fmaf(a4.y, v1.z, az); aw = fmaf(a4.y, v1.w, aw);
            ax = fmaf(a4.z, v2.x, ax); ay = fmaf(a4.z, v2.y, ay);
            az = fmaf(a4.z, v2.z, az); aw = fmaf(a4.z, v2.w, aw);
            ax = fmaf(a4.w, v3.x, ax); ay = fmaf(a4.w, v3.y, ay);
            az = fmaf(a4.w, v3.z, az); aw = fmaf(a4.w, v3.w, aw);
        }
        int hp = hh * 4 + hl;
        size_t sp = (size_t)d * 1024 + hp * 32 + wq;
        half4v o4;
        o4.x = (_Float16)ax; o4.y = (_Float16)ay; o4.z = (_Float16)az; o4.w = (_Float16)aw;
        *(half4v*)(outb + sp * 512 + q4 * 4) = o4;
    }
}

// ---------------------------------------------------------------------------
// K5: proj GEMM via MFMA + bias + layer_scale.
// out[b,co,s'] = (sum_c' wp[co,c'] * o_t[b,s',c'] + pb[co]) * ls[co]
// block tile 128(co) x 128(s'), K=512 in steps of 32.
// ---------------------------------------------------------------------------
__global__ __launch_bounds__(256)
void proj_mfma_kernel(const _Float16* __restrict__ o_t,
                      const _Float16* __restrict__ wp,
                      const float* __restrict__ pb,
                      const float* __restrict__ ls,
                      float* __restrict__ out)
{
    __shared__ _Float16 Ws[128 * 32];
    __shared__ _Float16 Xs[128 * 32];
    const int b = blockIdx.y;
    const int s_tile = blockIdx.x >> 1;
    const int o_tile = blockIdx.x & 1;
    const int s0 = s_tile * 128, o0 = o_tile * 128;
    const int t = threadIdx.x;
    const int w = t >> 6, l = t & 63;
    const int om = (w & 1) * 64, sn = (w >> 1) * 64;

    float4v acc[4][4];
#pragma unroll
    for (int i = 0; i < 4; i++)
#pragma unroll
        for (int j = 0; j < 4; j++) acc[i][j] = (float4v){0.f, 0.f, 0.f, 0.f};

    const _Float16* wg0 = wp + (size_t)(o0 + 32 * w + (l >> 2)) * 512 + (l & 3) * 8;
    const _Float16* xg0 = o_t + ((size_t)b * SS + s0 + 32 * w + (l >> 2)) * 512 + (l & 3) * 8;
    _Float16* wl = &Ws[(32 * w) * 32];
    _Float16* xl = &Xs[(32 * w) * 32];

    for (int c0 = 0; c0 < 512; c0 += 32) {
        gload16(wg0 + c0, wl);
        gload16(wg0 + 16 * 512 + c0, wl + 16 * 32);
        gload16(xg0 + c0, xl);
        gload16(xg0 + 16 * 512 + c0, xl + 16 * 32);
        __syncthreads();
        half8v a[4], bb[4];
#pragma unroll
        for (int i = 0; i < 4; i++)
            a[i] = *(const half8v*)&Ws[(om + i * 16 + (l & 15)) * 32 + (l >> 4) * 8];
#pragma unroll
        for (int j = 0; j < 4; j++)
            bb[j] = *(const half8v*)&Xs[(sn + j * 16 + (l & 15)) * 32 + (l >> 4) * 8];
#pragma unroll
        for (int i = 0; i < 4; i++)
#pragma unroll
            for (int j = 0; j < 4; j++)
                acc[i][j] = __builtin_amdgcn_mfma_f32_16x16x32_f16(a[i], bb[j], acc[i][j], 0, 0, 0);
        __syncthreads();
    }
    const int qd = l >> 4, m = l & 15;
#pragma unroll
    for (int i = 0; i < 4; i++) {
        float pbv[4], lsv[4];
#pragma unroll
        for (int r = 0; r < 4; r++) {
            int o = o0 + om + i * 16 + qd * 4 + r;
            pbv[r] = pb[o];
            lsv[r] = ls[o];
        }
#pragma unroll
        for (int j = 0; j < 4; j++) {
            int s = s0 + sn + j * 16 + m;
#pragma unroll
            for (int r = 0; r < 4; r++) {
                int o = o0 + om + i * 16 + qd * 4 + r;
                out[((size_t)b * 256 + o) * SS + s] = (acc[i][j][r] + pbv[r]) * lsv[r];
            }
        }
    }
}

extern "C" void kernel_launch(void* const* d_in, const int* in_sizes, int n_in,
                              void* d_out, int out_size, void* d_ws, size_t ws_size,
                              hipStream_t stream)
{
    const float* x      = (const float*)d_in[0];
    const float* q_w    = (const float*)d_in[1];
    const float* q_b    = (const float*)d_in[2];
    const float* kv_w   = (const float*)d_in[3];
    const float* kv_b   = (const float*)d_in[4];
    const float* proj_w = (const float*)d_in[5];
    const float* proj_b = (const float*)d_in[6];
    const float* ls     = (const float*)d_in[7];
    float* out = (float*)d_out;

    char* ws = (char*)d_ws;
    _Float16* x_t  = (_Float16*)(ws);                        // 33,554,432 B
    _Float16* q_t  = (_Float16*)(ws + 33554432);             // 67,108,864 B (reused as o_t)
    _Float16* kv_t = (_Float16*)(ws + 100663296);            // 16,777,216 B
    float*    Lbuf = (float*)   (ws + 117440512);            //     65,536 B
    _Float16* wq   = (_Float16*)(ws + 117506048);            //    262,144 B
    _Float16* wkv  = (_Float16*)(ws + 117768192);            //     65,536 B
    _Float16* wp   = (_Float16*)(ws + 117833728);            //    262,144 B
    _Float16* o_t  = q_t;  // q dead after logits

    hipMemsetAsync(Lbuf, 0, 65536, stream);

    cvt_x_kernel<<<dim3(512, 4, 2), 256, 0, stream>>>(x, x_t);
    cvt_w_kernel<<<dim3(128), 256, 0, stream>>>(q_w, wq);     // 131072 elems
    cvt_w_kernel<<<dim3(32),  256, 0, stream>>>(kv_w, wkv);   //  32768 elems
    cvt_w_kernel<<<dim3(128), 256, 0, stream>>>(proj_w, wp);  // 131072 elems

    conv_mfma_kernel<<<dim3(256 * 5, 2), 256, 0, stream>>>(x_t, wq, wkv, q_b, kv_b, q_t, kv_t);
    logits_mfma_kernel<<<dim3(32, 8, 2), 256, 0, stream>>>(q_t, kv_t, Lbuf);
    softmax_kernel<<<dim3(2), 256, 0, stream>>>(Lbuf);
    attn_v_kernel<<<dim3(32, 4, 2), 256, 0, stream>>>(kv_t, Lbuf, o_t);
    proj_mfma_kernel<<<dim3(256 * 2, 2), 256, 0, stream>>>(o_t, wp, proj_b, ls, out);
}